// Round 1
// baseline (7062.797 us; speedup 1.0000x reference)
//
#include <hip/hip_runtime.h>
#include <math.h>

// Decoder: 3 layers of cross-attention (q from h, k/v from x) + FF, then
// final scores out = (h@out_wq) @ (x@out_wk)^T / sqrt(512), shape (4,1024,2048).
//
// Reference reshape quirk: (B,Lq,512).reshape(B,8,-1,64) slices the FLAT
// (Lq*512) buffer, so head h / query q = packed row (h*Lq+q) of a
// (B, 8*Lq, 64) view. Q/K/V/attn-out all use this packing; projections
// remain plain row-major GEMMs on the (B*L, 512) view.

#define D_MODEL 512
#define NHEAD 8
#define DH 64
#define LQ 1024
#define LKK 2048
#define BB 4
#define NL 3

#define TS 64
#define KS 32

template<int TRANSB, int BIAS, int RELU>
__global__ __launch_bounds__(256) void gemm_kernel(
    const float* __restrict__ A, const float* __restrict__ Bm,
    const float* __restrict__ bias, float* __restrict__ C,
    int M, int N, int K, float scale,
    long sA, long sB, long sC)
{
    __shared__ float As[TS][KS + 1];
    __shared__ float Ws[KS][TS + 1];
    int tid = threadIdx.x;
    int tx = tid & 15, ty = tid >> 4;
    int col0 = blockIdx.x * TS;
    int row0 = blockIdx.y * TS;
    int z = blockIdx.z;
    const float* Ab = A + (long)z * sA;
    const float* Bb = Bm + (long)z * sB;
    float* Cb = C + (long)z * sC;

    float acc[4][4];
#pragma unroll
    for (int i = 0; i < 4; i++)
#pragma unroll
        for (int j = 0; j < 4; j++) acc[i][j] = 0.f;

    for (int k0 = 0; k0 < K; k0 += KS) {
#pragma unroll
        for (int t = 0; t < 8; t++) {           // A tile: 64x32
            int idx = tid + 256 * t;
            int r = idx >> 5, c = idx & 31;
            As[r][c] = Ab[(long)(row0 + r) * K + k0 + c];
        }
        if (TRANSB) {
#pragma unroll
            for (int t = 0; t < 8; t++) {       // B^T tile: stage transposed
                int idx = tid + 256 * t;
                int c = idx >> 5, kk = idx & 31;
                Ws[kk][c] = Bb[(long)(col0 + c) * K + k0 + kk];
            }
        } else {
#pragma unroll
            for (int t = 0; t < 8; t++) {       // B tile: 32x64
                int idx = tid + 256 * t;
                int r = idx >> 6, c = idx & 63;
                Ws[r][c] = Bb[(long)(k0 + r) * N + col0 + c];
            }
        }
        __syncthreads();
#pragma unroll
        for (int kk = 0; kk < KS; kk++) {
            float a[4], bv[4];
#pragma unroll
            for (int i = 0; i < 4; i++) a[i] = As[ty + 16 * i][kk];
#pragma unroll
            for (int j = 0; j < 4; j++) bv[j] = Ws[kk][tx + 16 * j];
#pragma unroll
            for (int i = 0; i < 4; i++)
#pragma unroll
                for (int j = 0; j < 4; j++) acc[i][j] += a[i] * bv[j];
        }
        __syncthreads();
    }
#pragma unroll
    for (int i = 0; i < 4; i++) {
        int row = row0 + ty + 16 * i;
#pragma unroll
        for (int j = 0; j < 4; j++) {
            int col = col0 + tx + 16 * j;
            float v = acc[i][j] * scale;
            if (BIAS) v += bias[col];
            if (RELU) v = fmaxf(v, 0.f);
            Cb[(long)row * N + col] = v;
        }
    }
}

// Flash-style cross attention on the packed (B, 8*L, 64) views.
// Grid: (LQ/16, B*NHEAD), block 256. 16 q-rows per block, K-tiles of 64.
__global__ __launch_bounds__(256) void attn_kernel(
    const float* __restrict__ QP, const float* __restrict__ KP,
    const float* __restrict__ VP, const int* __restrict__ mask,
    float* __restrict__ O)
{
    __shared__ float Qs[16][64];
    __shared__ float Ks[64][65];
    __shared__ float Vs[64][65];
    __shared__ float Sm[16][65];
    __shared__ float Oa[16][65];
    __shared__ float mrow[16], lrow[16], frow[16];

    int tid = threadIdx.x;
    int bh = blockIdx.y;
    int b = bh >> 3, h = bh & 7;
    int q0 = blockIdx.x * 16;

    long qbase = ((long)b * LQ * NHEAD + (long)h * LQ + q0) * DH;
#pragma unroll
    for (int t = 0; t < 4; t++) {
        int idx = tid + 256 * t;
        int r = idx >> 6, dd = idx & 63;
        Qs[r][dd] = QP[qbase + (long)r * DH + dd];
        Oa[r][dd] = 0.f;
    }
    if (tid < 16) { mrow[tid] = -1e30f; lrow[tid] = 0.f; }

    for (int kt = 0; kt < LKK / 64; kt++) {
        __syncthreads();
        long kbase = ((long)b * LKK * NHEAD + (long)h * LKK + kt * 64) * DH;
#pragma unroll
        for (int t = 0; t < 16; t++) {
            int idx = tid + 256 * t;
            int r = idx >> 6, dd = idx & 63;
            Ks[r][dd] = KP[kbase + (long)r * DH + dd];
            Vs[r][dd] = VP[kbase + (long)r * DH + dd];
        }
        __syncthreads();
        // scores: thread (c = tid&63) handles 4 rows
        {
            int c = tid & 63, rq = tid >> 6;
#pragma unroll
            for (int i = 0; i < 4; i++) {
                int r = rq * 4 + i;
                float s = 0.f;
#pragma unroll
                for (int dd = 0; dd < 64; dd++) s += Qs[r][dd] * Ks[c][dd];
                s *= 0.125f; // 1/sqrt(64)
                int mg = mask[((long)b * LQ + q0 + r) * LKK + kt * 64 + c];
                Sm[r][c] = mg ? -1e30f : s;
            }
        }
        __syncthreads();
        // online softmax update (serial per row; 16 threads)
        if (tid < 16) {
            int r = tid;
            float mold = mrow[r];
            float mmax = mold;
#pragma unroll
            for (int c = 0; c < 64; c++) mmax = fmaxf(mmax, Sm[r][c]);
            float fct = expf(mold - mmax);
            float sum = 0.f;
#pragma unroll
            for (int c = 0; c < 64; c++) {
                float p = expf(Sm[r][c] - mmax);
                Sm[r][c] = p;
                sum += p;
            }
            mrow[r] = mmax; frow[r] = fct;
            lrow[r] = lrow[r] * fct + sum;
        }
        __syncthreads();
        // PV: thread (dd = tid&63) handles 4 rows
        {
            int dd = tid & 63, rq = tid >> 6;
#pragma unroll
            for (int i = 0; i < 4; i++) {
                int r = rq * 4 + i;
                float acc = 0.f;
#pragma unroll
                for (int c = 0; c < 64; c++) acc += Sm[r][c] * Vs[c][dd];
                Oa[r][dd] = Oa[r][dd] * frow[r] + acc;
            }
        }
    }
    __syncthreads();
#pragma unroll
    for (int t = 0; t < 4; t++) {
        int idx = tid + 256 * t;
        int r = idx >> 6, dd = idx & 63;
        O[qbase + (long)r * DH + dd] = Oa[r][dd] / lrow[r];
    }
}

// out = LayerNorm(res + y) * g + b ; one wave per 512-elem row
__global__ __launch_bounds__(256) void ln_residual_kernel(
    const float* __restrict__ res, const float* __restrict__ y,
    const float* __restrict__ g, const float* __restrict__ bb,
    float* __restrict__ out)
{
    int wave = threadIdx.x >> 6, lane = threadIdx.x & 63;
    long row = (long)blockIdx.x * 4 + wave;
    const float* rp = res + row * D_MODEL;
    const float* yp = y + row * D_MODEL;
    float v[8];
    float s = 0.f, sq = 0.f;
#pragma unroll
    for (int j = 0; j < 8; j++) {
        int col = lane + 64 * j;
        v[j] = rp[col] + yp[col];
        s += v[j]; sq += v[j] * v[j];
    }
#pragma unroll
    for (int o = 32; o > 0; o >>= 1) {
        s += __shfl_down(s, o, 64);
        sq += __shfl_down(sq, o, 64);
    }
    s = __shfl(s, 0, 64);
    sq = __shfl(sq, 0, 64);
    float mean = s * (1.f / 512.f);
    float var = sq * (1.f / 512.f) - mean * mean;
    float rstd = rsqrtf(fmaxf(var, 0.f) + 1e-5f);
    float* op = out + row * D_MODEL;
#pragma unroll
    for (int j = 0; j < 8; j++) {
        int col = lane + 64 * j;
        op[col] = (v[j] - mean) * rstd * g[col] + bb[col];
    }
}

extern "C" void kernel_launch(void* const* d_in, const int* in_sizes, int n_in,
                              void* d_out, int out_size, void* d_ws, size_t ws_size,
                              hipStream_t stream)
{
    const float* x    = (const float*)d_in[0];   // (4,2048,512)
    const float* hin  = (const float*)d_in[1];   // (4,1024,512)
    const int*   mask = (const int*)d_in[2];     // (4,1024,2048) nonzero = masked
    const float* wq   = (const float*)d_in[3];
    const float* wk   = (const float*)d_in[4];
    const float* wv   = (const float*)d_in[5];
    const float* wo   = (const float*)d_in[6];
    const float* ffw1 = (const float*)d_in[7];
    const float* ffb1 = (const float*)d_in[8];
    const float* ffw2 = (const float*)d_in[9];
    const float* ffb2 = (const float*)d_in[10];
    const float* g1   = (const float*)d_in[11];
    const float* be1  = (const float*)d_in[12];
    const float* g2   = (const float*)d_in[13];
    const float* be2  = (const float*)d_in[14];
    const float* out_wq = (const float*)d_in[15];
    const float* out_wk = (const float*)d_in[16];
    float* out = (float*)d_out;

    const long NQ = (long)BB * LQ;   // 4096
    const long NK = (long)BB * LKK;  // 8192

    float* ws = (float*)d_ws;
    float* h_buf = ws;                       // 4096*512
    float* qp    = h_buf + NQ * D_MODEL;     // 4096*512
    float* kp    = qp + NQ * D_MODEL;        // 8192*512
    float* vp    = kp + NK * D_MODEL;        // 8192*512
    float* ao    = vp + NK * D_MODEL;        // 4096*512
    float* t0    = ao + NQ * D_MODEL;        // 4096*512
    // total: 16M floats = 64 MB

    hipMemcpyAsync(h_buf, hin, NQ * D_MODEL * sizeof(float),
                   hipMemcpyDeviceToDevice, stream);

    dim3 blk(256);
    dim3 gq(D_MODEL / TS, NQ / TS, 1);   // (8, 64)
    dim3 gk(D_MODEL / TS, NK / TS, 1);   // (8, 128)
    dim3 ga(LQ / 16, BB * NHEAD);        // (64, 32)

    for (int i = 0; i < NL; i++) {
        const float* wqi = wq + (long)i * D_MODEL * D_MODEL;
        const float* wki = wk + (long)i * D_MODEL * D_MODEL;
        const float* wvi = wv + (long)i * D_MODEL * D_MODEL;
        const float* woi = wo + (long)i * D_MODEL * D_MODEL;
        const float* w1i = ffw1 + (long)i * D_MODEL * D_MODEL;
        const float* w2i = ffw2 + (long)i * D_MODEL * D_MODEL;

        gemm_kernel<0,0,0><<<gq, blk, 0, stream>>>(h_buf, wqi, nullptr, qp,
            (int)NQ, D_MODEL, D_MODEL, 1.f, 0, 0, 0);
        gemm_kernel<0,0,0><<<gk, blk, 0, stream>>>(x, wki, nullptr, kp,
            (int)NK, D_MODEL, D_MODEL, 1.f, 0, 0, 0);
        gemm_kernel<0,0,0><<<gk, blk, 0, stream>>>(x, wvi, nullptr, vp,
            (int)NK, D_MODEL, D_MODEL, 1.f, 0, 0, 0);

        attn_kernel<<<ga, blk, 0, stream>>>(qp, kp, vp, mask, ao);

        gemm_kernel<0,0,0><<<gq, blk, 0, stream>>>(ao, woi, nullptr, t0,
            (int)NQ, D_MODEL, D_MODEL, 1.f, 0, 0, 0);
        ln_residual_kernel<<<NQ / 4, blk, 0, stream>>>(h_buf, t0,
            g1 + i * D_MODEL, be1 + i * D_MODEL, h_buf);

        gemm_kernel<0,1,1><<<gq, blk, 0, stream>>>(h_buf, w1i,
            ffb1 + i * D_MODEL, t0, (int)NQ, D_MODEL, D_MODEL, 1.f, 0, 0, 0);
        gemm_kernel<0,1,0><<<gq, blk, 0, stream>>>(t0, w2i,
            ffb2 + i * D_MODEL, vp, (int)NQ, D_MODEL, D_MODEL, 1.f, 0, 0, 0);
        ln_residual_kernel<<<NQ / 4, blk, 0, stream>>>(h_buf, vp,
            g2 + i * D_MODEL, be2 + i * D_MODEL, h_buf);
    }

    // final: qf = h @ out_wq ; kf = x @ out_wk ; out = qf @ kf^T / sqrt(512)
    gemm_kernel<0,0,0><<<gq, blk, 0, stream>>>(h_buf, out_wq, nullptr, qp,
        (int)NQ, D_MODEL, D_MODEL, 1.f, 0, 0, 0);
    gemm_kernel<0,0,0><<<gk, blk, 0, stream>>>(x, out_wk, nullptr, kp,
        (int)NK, D_MODEL, D_MODEL, 1.f, 0, 0, 0);

    dim3 gf(LKK / TS, LQ / TS, BB);  // (32, 16, 4)
    gemm_kernel<1,0,0><<<gf, blk, 0, stream>>>(qp, kp, nullptr, out,
        LQ, LKK, D_MODEL, 0.044194173824159216f,
        (long)LQ * D_MODEL, (long)LKK * D_MODEL, (long)LQ * LKK);
}

// Round 2
// 714.593 us; speedup vs baseline: 9.8837x; 9.8837x over previous
//
#include <hip/hip_runtime.h>
#include <math.h>

// bf16-MFMA decoder. All GEMMs NT (pre-transposed bf16 weights), m97-style
// global_load_lds staging. Flash attention with MFMA QK^T / PV and
// wave-parallel online softmax. fp32 kept on residual+LN path only.

#define D_MODEL 512
#define LQ 1024
#define LKK 2048
#define BB 4
#define NL 3

typedef __bf16 bf16;
typedef __bf16 bf16x8 __attribute__((ext_vector_type(8)));
typedef __bf16 bf16x4 __attribute__((ext_vector_type(4)));
typedef float f32x4 __attribute__((ext_vector_type(4)));

__device__ inline f32x4 mfma16(bf16x8 a, bf16x8 b, f32x4 c) {
    return __builtin_amdgcn_mfma_f32_16x16x32_bf16(a, b, c, 0, 0, 0);
}

__device__ inline void gload16(const void* g, void* l) {
    __builtin_amdgcn_global_load_lds(
        (const __attribute__((address_space(1))) void*)g,
        (__attribute__((address_space(3))) void*)l, 16, 0, 0);
}

// ---------------- cast fp32 -> bf16 (vectorized) ----------------
__global__ __launch_bounds__(256) void cast_kernel(
    const float* __restrict__ in, bf16* __restrict__ out, long n)
{
    long i4 = ((long)blockIdx.x * 256 + threadIdx.x) * 4;
    if (i4 >= n) return;
    float4 v = *(const float4*)(in + i4);
    bf16x4 o;
    o[0] = (bf16)v.x; o[1] = (bf16)v.y; o[2] = (bf16)v.z; o[3] = (bf16)v.w;
    *(bf16x4*)(out + i4) = o;
}

// ------------- transpose-cast: W[512][512] fp32 -> Wt[512][512] bf16 -------------
__global__ __launch_bounds__(256) void tcast_kernel(
    const float* __restrict__ in, bf16* __restrict__ out)
{
    __shared__ float t[32][33];
    long zo = (long)blockIdx.z * 262144;
    int tx = threadIdx.x & 31, ty = threadIdx.x >> 5;
    int x0 = blockIdx.x * 32, y0 = blockIdx.y * 32;
#pragma unroll
    for (int i = 0; i < 4; i++)
        t[ty + 8 * i][tx] = in[zo + (long)(y0 + ty + 8 * i) * 512 + x0 + tx];
    __syncthreads();
#pragma unroll
    for (int i = 0; i < 4; i++)
        out[zo + (long)(x0 + ty + 8 * i) * 512 + y0 + tx] = (bf16)t[tx][ty + 8 * i];
}

// ------------- mask (int32) -> packed bits -------------
__global__ __launch_bounds__(256) void maskbits_kernel(
    const int* __restrict__ m, unsigned* __restrict__ bits)
{
    long i = (long)blockIdx.x * 256 + threadIdx.x;
    int v = m[i] != 0;
    unsigned long long bal = __ballot(v);
    int lane = threadIdx.x & 63;
    if (lane == 0) bits[i >> 5] = (unsigned)bal;
    else if (lane == 32) bits[i >> 5] = (unsigned)(bal >> 32);
}

// ------------- MFMA GEMM: C[M,N] = A[M,K] @ Bt[N,K]^T -------------
// BM=128, BN=64, BK=32. 256 threads = 4 waves (2x2), each wave 64x32.
template<int BIAS, int RELU, int OUT_BF16>
__global__ __launch_bounds__(256) void mfma_gemm(
    const bf16* __restrict__ A, const bf16* __restrict__ Bt,
    const float* __restrict__ bias, void* __restrict__ Cv,
    int N, int K, float scale, long sA, long sB, long sC)
{
    __shared__ bf16 As[128][32];
    __shared__ bf16 Bs[64][32];
    int tid = threadIdx.x;
    int lane = tid & 63, w = tid >> 6;
    int wr = w >> 1, wc = w & 1;
    int g = lane >> 4, c = lane & 15;
    long z = blockIdx.z;
    const bf16* Ab = A + z * sA;
    const bf16* Bb = Bt + z * sB;
    long row0 = (long)blockIdx.y * 128;
    int n0 = blockIdx.x * 64;

    f32x4 acc[4][2];
#pragma unroll
    for (int m = 0; m < 4; m++)
#pragma unroll
        for (int n = 0; n < 2; n++) acc[m][n] = (f32x4){0.f, 0.f, 0.f, 0.f};

    for (int k0 = 0; k0 < K; k0 += 32) {
        __syncthreads();
        const bf16* ga = Ab + (row0 + w * 32 + (lane >> 2)) * K + k0 + (lane & 3) * 8;
        gload16(ga, &As[w * 32][0]);
        gload16(ga + (long)16 * K, &As[w * 32 + 16][0]);
        const bf16* gb = Bb + (long)(n0 + w * 16 + (lane >> 2)) * K + k0 + (lane & 3) * 8;
        gload16(gb, &Bs[w * 16][0]);
        __syncthreads();
        bf16x8 af[4], bfr[2];
#pragma unroll
        for (int m = 0; m < 4; m++)
            af[m] = *(const bf16x8*)&As[wr * 64 + m * 16 + c][g * 8];
#pragma unroll
        for (int n = 0; n < 2; n++)
            bfr[n] = *(const bf16x8*)&Bs[wc * 32 + n * 16 + c][g * 8];
#pragma unroll
        for (int m = 0; m < 4; m++)
#pragma unroll
            for (int n = 0; n < 2; n++)
                acc[m][n] = mfma16(af[m], bfr[n], acc[m][n]);
    }

    float bv[2] = {0.f, 0.f};
    if (BIAS) {
#pragma unroll
        for (int n = 0; n < 2; n++) bv[n] = bias[n0 + wc * 32 + n * 16 + c];
    }
    float* Cf = (float*)Cv + z * sC;
    bf16* Cb = (bf16*)Cv + z * sC;
#pragma unroll
    for (int m = 0; m < 4; m++)
#pragma unroll
        for (int n = 0; n < 2; n++)
#pragma unroll
            for (int j = 0; j < 4; j++) {
                long row = row0 + wr * 64 + m * 16 + g * 4 + j;
                int col = n0 + wc * 32 + n * 16 + c;
                float v = acc[m][n][j] * scale;
                if (BIAS) v += bv[n];
                if (RELU) v = fmaxf(v, 0.f);
                if (OUT_BF16) Cb[row * N + col] = (bf16)v;
                else Cf[row * N + col] = v;
            }
}

// ------------- MFMA flash attention -------------
// Packed views: Q rows (b*8 + h)*1024 + p, K/V rows (b*8 + h)*2048 + p, dh=64.
// Block: 64 q-rows (4 waves x 16), K-step 64 keys. Grid (LQ/64, B*8).
__global__ __launch_bounds__(256) void attn_mfma(
    const bf16* __restrict__ QP, const bf16* __restrict__ KP,
    const bf16* __restrict__ VP, const unsigned* __restrict__ bits,
    bf16* __restrict__ O)
{
    __shared__ bf16 Vt[64][72];        // V transposed [d][key], padded
    __shared__ bf16 Pl[4][16][72];     // per-wave P tile [q][key], padded

    int tid = threadIdx.x;
    int lane = tid & 63, wv = tid >> 6;
    int g = lane >> 4, c = lane & 15;
    int bh = blockIdx.y, b = bh >> 3, h = bh & 7;
    int q0 = blockIdx.x * 64;

    long qrow0 = (long)b * 8192 + (long)h * 1024 + q0 + wv * 16;
    long kvrow0 = (long)b * 16384 + (long)h * 2048;
    const unsigned* bitrow = bits + ((long)b * 1024 + q0 + wv * 16) * 64;

    bf16x8 qa[2];
#pragma unroll
    for (int hh = 0; hh < 2; hh++)
        qa[hh] = *(const bf16x8*)(QP + (qrow0 + c) * 64 + hh * 32 + g * 8);

    f32x4 o_acc[4];
#pragma unroll
    for (int ot = 0; ot < 4; ot++) o_acc[ot] = (f32x4){0.f, 0.f, 0.f, 0.f};
    float m_r[4], l_r[4];
#pragma unroll
    for (int j = 0; j < 4; j++) { m_r[j] = -1e30f; l_r[j] = 0.f; }

    for (int kt = 0; kt < LKK / 64; kt++) {
        int k0 = kt * 64;
        __syncthreads();
        // stage V transposed: wave wv covers d-chunks {wv*8, wv*8+32}
        {
            int key = tid & 63;
#pragma unroll
            for (int it = 0; it < 2; it++) {
                int dbase = wv * 8 + it * 32;
                bf16x8 vv = *(const bf16x8*)(VP + (kvrow0 + k0 + key) * 64 + dbase);
#pragma unroll
                for (int jj = 0; jj < 8; jj++) Vt[dbase + jj][key] = vv[jj];
            }
        }
        __syncthreads();

        // S = Q K^T  (4 n-tiles of 16 keys, 2 MFMAs each over d)
        f32x4 s[4];
#pragma unroll
        for (int nt = 0; nt < 4; nt++) {
            const bf16* krow = KP + (kvrow0 + k0 + nt * 16 + c) * 64;
            bf16x8 kb0 = *(const bf16x8*)(krow + g * 8);
            bf16x8 kb1 = *(const bf16x8*)(krow + 32 + g * 8);
            s[nt] = mfma16(qa[0], kb0, (f32x4){0.f, 0.f, 0.f, 0.f});
            s[nt] = mfma16(qa[1], kb1, s[nt]);
        }

        // scale + mask (packed bits; per row j one uint2 broadcast)
        float fct[4];
#pragma unroll
        for (int j = 0; j < 4; j++) {
            uint2 wp = *(const uint2*)(bitrow + (long)(4 * g + j) * 64 + (k0 >> 5));
#pragma unroll
            for (int nt = 0; nt < 4; nt++) {
                unsigned wsel = (nt < 2) ? wp.x : wp.y;
                int sh = (nt & 1) * 16 + c;
                if ((wsel >> sh) & 1) s[nt][j] = -1e30f;
                else s[nt][j] *= 0.125f;
            }
            // row max across 4 n-tiles then across the 16 lanes of the group
            float mx = fmaxf(fmaxf(s[0][j], s[1][j]), fmaxf(s[2][j], s[3][j]));
            mx = fmaxf(mx, __shfl_xor(mx, 1));
            mx = fmaxf(mx, __shfl_xor(mx, 2));
            mx = fmaxf(mx, __shfl_xor(mx, 4));
            mx = fmaxf(mx, __shfl_xor(mx, 8));
            float mnew = fmaxf(m_r[j], mx);
            fct[j] = __expf(m_r[j] - mnew);
            float sum = 0.f;
#pragma unroll
            for (int nt = 0; nt < 4; nt++) {
                float p = __expf(s[nt][j] - mnew);
                s[nt][j] = p;
                sum += p;
            }
            sum += __shfl_xor(sum, 1);
            sum += __shfl_xor(sum, 2);
            sum += __shfl_xor(sum, 4);
            sum += __shfl_xor(sum, 8);
            l_r[j] = l_r[j] * fct[j] + sum;
            m_r[j] = mnew;
        }

        // rescale O, write P to per-wave LDS in A-frag layout
#pragma unroll
        for (int ot = 0; ot < 4; ot++)
#pragma unroll
            for (int j = 0; j < 4; j++) o_acc[ot][j] *= fct[j];
#pragma unroll
        for (int nt = 0; nt < 4; nt++)
#pragma unroll
            for (int j = 0; j < 4; j++)
                Pl[wv][4 * g + j][nt * 16 + c] = (bf16)s[nt][j];

        // PV: O += P @ V   (A = P frags, B = Vt frags)
#pragma unroll
        for (int kh = 0; kh < 2; kh++) {
            bf16x8 pa = *(const bf16x8*)&Pl[wv][c][kh * 32 + g * 8];
#pragma unroll
            for (int ot = 0; ot < 4; ot++) {
                bf16x8 vb = *(const bf16x8*)&Vt[ot * 16 + c][kh * 32 + g * 8];
                o_acc[ot] = mfma16(pa, vb, o_acc[ot]);
            }
        }
    }

    float inv[4];
#pragma unroll
    for (int j = 0; j < 4; j++) inv[j] = 1.f / l_r[j];
#pragma unroll
    for (int ot = 0; ot < 4; ot++)
#pragma unroll
        for (int j = 0; j < 4; j++)
            O[(qrow0 + 4 * g + j) * 64 + ot * 16 + c] = (bf16)(o_acc[ot][j] * inv[j]);
}

// ------------- LN(residual): h = LN(h + y); writes fp32 + bf16 -------------
__global__ __launch_bounds__(256) void ln_kernel(
    const float* __restrict__ res, const float* __restrict__ y,
    const float* __restrict__ g, const float* __restrict__ bb,
    float* __restrict__ outf, bf16* __restrict__ outb)
{
    int wave = threadIdx.x >> 6, lane = threadIdx.x & 63;
    long row = (long)blockIdx.x * 4 + wave;
    const float* rp = res + row * D_MODEL;
    const float* yp = y + row * D_MODEL;
    float v[8];
    float s = 0.f, sq = 0.f;
#pragma unroll
    for (int j = 0; j < 8; j++) {
        int col = lane + 64 * j;
        v[j] = rp[col] + yp[col];
        s += v[j]; sq += v[j] * v[j];
    }
#pragma unroll
    for (int o = 32; o > 0; o >>= 1) {
        s += __shfl_down(s, o, 64);
        sq += __shfl_down(sq, o, 64);
    }
    s = __shfl(s, 0, 64);
    sq = __shfl(sq, 0, 64);
    float mean = s * (1.f / 512.f);
    float var = sq * (1.f / 512.f) - mean * mean;
    float rstd = rsqrtf(fmaxf(var, 0.f) + 1e-5f);
    float* opf = outf + row * D_MODEL;
    bf16* opb = outb + row * D_MODEL;
#pragma unroll
    for (int j = 0; j < 8; j++) {
        int col = lane + 64 * j;
        float o = (v[j] - mean) * rstd * g[col] + bb[col];
        opf[col] = o;
        opb[col] = (bf16)o;
    }
}

extern "C" void kernel_launch(void* const* d_in, const int* in_sizes, int n_in,
                              void* d_out, int out_size, void* d_ws, size_t ws_size,
                              hipStream_t stream)
{
    const float* x    = (const float*)d_in[0];
    const float* hin  = (const float*)d_in[1];
    const int*   mask = (const int*)d_in[2];
    const float* wq   = (const float*)d_in[3];
    const float* wk   = (const float*)d_in[4];
    const float* wv   = (const float*)d_in[5];
    const float* wo   = (const float*)d_in[6];
    const float* ffw1 = (const float*)d_in[7];
    const float* ffb1 = (const float*)d_in[8];
    const float* ffw2 = (const float*)d_in[9];
    const float* ffb2 = (const float*)d_in[10];
    const float* g1   = (const float*)d_in[11];
    const float* be1  = (const float*)d_in[12];
    const float* g2   = (const float*)d_in[13];
    const float* be2  = (const float*)d_in[14];
    const float* out_wq = (const float*)d_in[15];
    const float* out_wk = (const float*)d_in[16];
    float* out = (float*)d_out;

    const long NQ = (long)BB * LQ;   // 4096
    const long NK = (long)BB * LKK;  // 8192
    const long WSZ = 512L * 512;     // 262144 per weight matrix

    char* W = (char*)d_ws;
    float* h_f  = (float*)(W);                      //  8 MB
    float* y_f  = (float*)(W + 8388608);            //  8 MB
    bf16*  h_b  = (bf16*)(W + 16777216);            //  4 MB
    bf16*  x_b  = (bf16*)(W + 20971520);            //  8 MB
    bf16*  q_b  = (bf16*)(W + 29360128);            //  4 MB (also FF1-out)
    bf16*  k_b  = (bf16*)(W + 33554432);            //  8 MB
    bf16*  v_b  = (bf16*)(W + 41943040);            //  8 MB
    bf16*  a_b  = (bf16*)(W + 50331648);            //  4 MB
    bf16*  wt   = (bf16*)(W + 54525952);            // 10 MB (20 matrices, NT)
    unsigned* mb = (unsigned*)(W + 65011712);       //  1 MB

    bf16* wtq = wt;            bf16* wtk = wt + 3 * WSZ;
    bf16* wtv = wt + 6 * WSZ;  bf16* wto = wt + 9 * WSZ;
    bf16* wt1 = wt + 12 * WSZ; bf16* wt2 = wt + 15 * WSZ;
    bf16* wtoq = wt + 18 * WSZ; bf16* wtok = wt + 19 * WSZ;

    dim3 blk(256);

    // preprocessing
    hipMemcpyAsync(h_f, hin, NQ * D_MODEL * sizeof(float),
                   hipMemcpyDeviceToDevice, stream);
    cast_kernel<<<dim3((NK * D_MODEL / 4 + 255) / 256), blk, 0, stream>>>(x, x_b, NK * D_MODEL);
    cast_kernel<<<dim3((NQ * D_MODEL / 4 + 255) / 256), blk, 0, stream>>>(hin, h_b, NQ * D_MODEL);
    dim3 gt(16, 16, 3);
    tcast_kernel<<<gt, blk, 0, stream>>>(wq, wtq);
    tcast_kernel<<<gt, blk, 0, stream>>>(wk, wtk);
    tcast_kernel<<<gt, blk, 0, stream>>>(wv, wtv);
    tcast_kernel<<<gt, blk, 0, stream>>>(wo, wto);
    tcast_kernel<<<gt, blk, 0, stream>>>(ffw1, wt1);
    tcast_kernel<<<gt, blk, 0, stream>>>(ffw2, wt2);
    dim3 gt1(16, 16, 1);
    tcast_kernel<<<gt1, blk, 0, stream>>>(out_wq, wtoq);
    tcast_kernel<<<gt1, blk, 0, stream>>>(out_wk, wtok);
    maskbits_kernel<<<dim3(32768), blk, 0, stream>>>(mask, mb);

    dim3 gq(8, 32, 1);    // 4096 x 512
    dim3 gk(8, 64, 1);    // 8192 x 512
    dim3 ga(LQ / 64, BB * 8);

    for (int i = 0; i < NL; i++) {
        mfma_gemm<0,0,1><<<gq, blk, 0, stream>>>(h_b, wtq + i * WSZ, nullptr, q_b,
            512, 512, 1.f, 0, 0, 0);
        mfma_gemm<0,0,1><<<gk, blk, 0, stream>>>(x_b, wtk + i * WSZ, nullptr, k_b,
            512, 512, 1.f, 0, 0, 0);
        mfma_gemm<0,0,1><<<gk, blk, 0, stream>>>(x_b, wtv + i * WSZ, nullptr, v_b,
            512, 512, 1.f, 0, 0, 0);

        attn_mfma<<<ga, blk, 0, stream>>>(q_b, k_b, v_b, mb, a_b);

        mfma_gemm<0,0,0><<<gq, blk, 0, stream>>>(a_b, wto + i * WSZ, nullptr, y_f,
            512, 512, 1.f, 0, 0, 0);
        ln_kernel<<<dim3(NQ / 4), blk, 0, stream>>>(h_f, y_f,
            g1 + i * D_MODEL, be1 + i * D_MODEL, h_f, h_b);

        mfma_gemm<1,1,1><<<gq, blk, 0, stream>>>(h_b, wt1 + i * WSZ,
            ffb1 + i * D_MODEL, q_b, 512, 512, 1.f, 0, 0, 0);
        mfma_gemm<1,0,0><<<gq, blk, 0, stream>>>(q_b, wt2 + i * WSZ,
            ffb2 + i * D_MODEL, y_f, 512, 512, 1.f, 0, 0, 0);
        ln_kernel<<<dim3(NQ / 4), blk, 0, stream>>>(h_f, y_f,
            g2 + i * D_MODEL, be2 + i * D_MODEL, h_f, h_b);
    }

    // final scores
    mfma_gemm<0,0,1><<<gq, blk, 0, stream>>>(h_b, wtoq, nullptr, q_b,
        512, 512, 1.f, 0, 0, 0);
    mfma_gemm<0,0,1><<<gk, blk, 0, stream>>>(x_b, wtok, nullptr, k_b,
        512, 512, 1.f, 0, 0, 0);
    dim3 gf(LKK / 64, LQ / 128, BB);
    mfma_gemm<0,0,0><<<gf, blk, 0, stream>>>(q_b, k_b, nullptr, out,
        LKK, 512, 0.04419417382415922f,
        (long)LQ * 512, (long)LKK * 512, (long)LQ * LKK);
}

// Round 3
// 649.093 us; speedup vs baseline: 10.8810x; 1.1009x over previous
//
#include <hip/hip_runtime.h>
#include <math.h>

// bf16-MFMA decoder, round 3.
// - Attention: swapped QK^T (S^T = K x Q) so softmax is lane-local per q-row:
//   2 shfl_xor per reduction instead of 32 ds_swizzles per tile.
// - K/V projections batched (z=2) into an m97-style 128x128 MFMA GEMM;
//   same kernel for final kf and batched final scores.

#define D_MODEL 512
#define LQ 1024
#define LKK 2048
#define BB 4
#define NL 3

typedef __bf16 bf16;
typedef __bf16 bf16x8 __attribute__((ext_vector_type(8)));
typedef __bf16 bf16x4 __attribute__((ext_vector_type(4)));
typedef float f32x4 __attribute__((ext_vector_type(4)));

__device__ inline f32x4 mfma16(bf16x8 a, bf16x8 b, f32x4 c) {
    return __builtin_amdgcn_mfma_f32_16x16x32_bf16(a, b, c, 0, 0, 0);
}

__device__ inline void gload16(const void* g, void* l) {
    __builtin_amdgcn_global_load_lds(
        (const __attribute__((address_space(1))) void*)g,
        (__attribute__((address_space(3))) void*)l, 16, 0, 0);
}

// ---------------- cast fp32 -> bf16 ----------------
__global__ __launch_bounds__(256) void cast_kernel(
    const float* __restrict__ in, bf16* __restrict__ out, long n)
{
    long i4 = ((long)blockIdx.x * 256 + threadIdx.x) * 4;
    if (i4 >= n) return;
    float4 v = *(const float4*)(in + i4);
    bf16x4 o;
    o[0] = (bf16)v.x; o[1] = (bf16)v.y; o[2] = (bf16)v.z; o[3] = (bf16)v.w;
    *(bf16x4*)(out + i4) = o;
}

// ------- transpose-cast W[512][512] fp32 -> bf16, strided dst per z -------
__global__ __launch_bounds__(256) void tcast_kernel(
    const float* __restrict__ in, bf16* __restrict__ out, long dstride)
{
    __shared__ float t[32][33];
    const float* ip = in + (long)blockIdx.z * 262144;
    bf16* op = out + (long)blockIdx.z * dstride;
    int tx = threadIdx.x & 31, ty = threadIdx.x >> 5;
    int x0 = blockIdx.x * 32, y0 = blockIdx.y * 32;
#pragma unroll
    for (int i = 0; i < 4; i++)
        t[ty + 8 * i][tx] = ip[(long)(y0 + ty + 8 * i) * 512 + x0 + tx];
    __syncthreads();
#pragma unroll
    for (int i = 0; i < 4; i++)
        op[(long)(x0 + ty + 8 * i) * 512 + y0 + tx] = (bf16)t[tx][ty + 8 * i];
}

// ------------- mask (int32) -> packed bits -------------
__global__ __launch_bounds__(256) void maskbits_kernel(
    const int* __restrict__ m, unsigned* __restrict__ bits)
{
    long i = (long)blockIdx.x * 256 + threadIdx.x;
    int v = m[i] != 0;
    unsigned long long bal = __ballot(v);
    int lane = threadIdx.x & 63;
    if (lane == 0) bits[i >> 5] = (unsigned)bal;
    else if (lane == 32) bits[i >> 5] = (unsigned)(bal >> 32);
}

// ------------- 128x64 MFMA GEMM (small-N projections) -------------
template<int BIAS, int RELU, int OUT_BF16>
__global__ __launch_bounds__(256) void mfma_gemm(
    const bf16* __restrict__ A, const bf16* __restrict__ Bt,
    const float* __restrict__ bias, void* __restrict__ Cv,
    int N, int K, float scale, long sA, long sB, long sC)
{
    __shared__ bf16 As[128][32];
    __shared__ bf16 Bs[64][32];
    int tid = threadIdx.x;
    int lane = tid & 63, w = tid >> 6;
    int wr = w >> 1, wc = w & 1;
    int g = lane >> 4, c = lane & 15;
    long z = blockIdx.z;
    const bf16* Ab = A + z * sA;
    const bf16* Bb = Bt + z * sB;
    long row0 = (long)blockIdx.y * 128;
    int n0 = blockIdx.x * 64;

    f32x4 acc[4][2];
#pragma unroll
    for (int m = 0; m < 4; m++)
#pragma unroll
        for (int n = 0; n < 2; n++) acc[m][n] = (f32x4){0.f, 0.f, 0.f, 0.f};

    for (int k0 = 0; k0 < K; k0 += 32) {
        __syncthreads();
        const bf16* ga = Ab + (row0 + w * 32 + (lane >> 2)) * K + k0 + (lane & 3) * 8;
        gload16(ga, &As[w * 32][0]);
        gload16(ga + (long)16 * K, &As[w * 32 + 16][0]);
        const bf16* gb = Bb + (long)(n0 + w * 16 + (lane >> 2)) * K + k0 + (lane & 3) * 8;
        gload16(gb, &Bs[w * 16][0]);
        __syncthreads();
        bf16x8 af[4], bfr[2];
#pragma unroll
        for (int m = 0; m < 4; m++)
            af[m] = *(const bf16x8*)&As[wr * 64 + m * 16 + c][g * 8];
#pragma unroll
        for (int n = 0; n < 2; n++)
            bfr[n] = *(const bf16x8*)&Bs[wc * 32 + n * 16 + c][g * 8];
#pragma unroll
        for (int m = 0; m < 4; m++)
#pragma unroll
            for (int n = 0; n < 2; n++)
                acc[m][n] = mfma16(af[m], bfr[n], acc[m][n]);
    }

    float bv[2] = {0.f, 0.f};
    if (BIAS) {
#pragma unroll
        for (int n = 0; n < 2; n++) bv[n] = bias[n0 + wc * 32 + n * 16 + c];
    }
    float* Cf = (float*)Cv + z * sC;
    bf16* Cb = (bf16*)Cv + z * sC;
#pragma unroll
    for (int m = 0; m < 4; m++)
#pragma unroll
        for (int n = 0; n < 2; n++)
#pragma unroll
            for (int j = 0; j < 4; j++) {
                long row = row0 + wr * 64 + m * 16 + g * 4 + j;
                int col = n0 + wc * 32 + n * 16 + c;
                float v = acc[m][n][j] * scale;
                if (BIAS) v += bv[n];
                if (RELU) v = fmaxf(v, 0.f);
                if (OUT_BF16) Cb[row * N + col] = (bf16)v;
                else Cf[row * N + col] = v;
            }
}

// ------------- 128x128 MFMA GEMM (m97 structure; big GEMMs) -------------
template<int OUT_BF16>
__global__ __launch_bounds__(256) void mfma_gemm128(
    const bf16* __restrict__ A, const bf16* __restrict__ Bt,
    void* __restrict__ Cv, int N, int K, float scale,
    long sA, long sB, long sC)
{
    __shared__ bf16 As[128][32];
    __shared__ bf16 Bs[128][32];
    int tid = threadIdx.x;
    int lane = tid & 63, w = tid >> 6;
    int wr = w >> 1, wc = w & 1;
    int g = lane >> 4, c = lane & 15;
    long z = blockIdx.z;
    const bf16* Ab = A + z * sA;
    const bf16* Bb = Bt + z * sB;
    long row0 = (long)blockIdx.y * 128;
    int n0 = blockIdx.x * 128;

    f32x4 acc[4][4];
#pragma unroll
    for (int m = 0; m < 4; m++)
#pragma unroll
        for (int n = 0; n < 4; n++) acc[m][n] = (f32x4){0.f, 0.f, 0.f, 0.f};

    for (int k0 = 0; k0 < K; k0 += 32) {
        __syncthreads();
        const bf16* ga = Ab + (row0 + w * 16 + (lane >> 2)) * K + k0 + (lane & 3) * 8;
        gload16(ga, &As[w * 16][0]);
        gload16(ga + (long)64 * K, &As[w * 16 + 64][0]);
        const bf16* gb = Bb + (long)(n0 + w * 16 + (lane >> 2)) * K + k0 + (lane & 3) * 8;
        gload16(gb, &Bs[w * 16][0]);
        gload16(gb + (long)64 * K, &Bs[w * 16 + 64][0]);
        __syncthreads();
        bf16x8 af[4], bfr[4];
#pragma unroll
        for (int m = 0; m < 4; m++)
            af[m] = *(const bf16x8*)&As[wr * 64 + m * 16 + c][g * 8];
#pragma unroll
        for (int n = 0; n < 4; n++)
            bfr[n] = *(const bf16x8*)&Bs[wc * 64 + n * 16 + c][g * 8];
#pragma unroll
        for (int m = 0; m < 4; m++)
#pragma unroll
            for (int n = 0; n < 4; n++)
                acc[m][n] = mfma16(af[m], bfr[n], acc[m][n]);
    }

    float* Cf = (float*)Cv + z * sC;
    bf16* Cb = (bf16*)Cv + z * sC;
#pragma unroll
    for (int m = 0; m < 4; m++)
#pragma unroll
        for (int n = 0; n < 4; n++)
#pragma unroll
            for (int j = 0; j < 4; j++) {
                long row = row0 + wr * 64 + m * 16 + g * 4 + j;
                int col = n0 + wc * 64 + n * 16 + c;
                float v = acc[m][n][j] * scale;
                if (OUT_BF16) Cb[row * N + col] = (bf16)v;
                else Cf[row * N + col] = v;
            }
}

// ------------- MFMA flash attention, swapped QK^T -------------
// Block: 64 q-rows (4 waves x 16), K-step 64 keys. Grid (LQ/64, B*8).
// Swapped S^T = mfma(K, Q): lane owns q = lane&15; keys 16*mt+4*g+j lane-local.
__global__ __launch_bounds__(256) void attn_mfma(
    const bf16* __restrict__ QP, const bf16* __restrict__ KP,
    const bf16* __restrict__ VP, const unsigned* __restrict__ bits,
    bf16* __restrict__ O)
{
    __shared__ bf16 Vt[64][72];        // V transposed [d][key]
    __shared__ bf16 Pl[4][16][72];     // per-wave P [q=c][key]

    int tid = threadIdx.x;
    int lane = tid & 63, wv = tid >> 6;
    int g = lane >> 4, c = lane & 15;
    int bh = blockIdx.y, b = bh >> 3, h = bh & 7;
    int q0 = blockIdx.x * 64;

    long qrow0 = (long)b * 8192 + (long)h * 1024 + q0 + wv * 16;
    long kvrow0 = (long)b * 16384 + (long)h * 2048;
    const unsigned* bitrow = bits + ((long)b * 1024 + q0 + wv * 16 + c) * 64;

    bf16x8 qa[2];
#pragma unroll
    for (int hh = 0; hh < 2; hh++)
        qa[hh] = *(const bf16x8*)(QP + (qrow0 + c) * 64 + hh * 32 + g * 8);

    f32x4 o_acc[4];
#pragma unroll
    for (int ot = 0; ot < 4; ot++) o_acc[ot] = (f32x4){0.f, 0.f, 0.f, 0.f};
    float m_r = -1e30f, l_r = 0.f;     // per lane: stats for q = c

    for (int kt = 0; kt < LKK / 64; kt++) {
        int k0 = kt * 64;
        __syncthreads();
        // stage V transposed (4 waves cooperate)
        {
            int key = tid & 63;
#pragma unroll
            for (int it = 0; it < 2; it++) {
                int dbase = wv * 8 + it * 32;
                bf16x8 vv = *(const bf16x8*)(VP + (kvrow0 + k0 + key) * 64 + dbase);
#pragma unroll
                for (int jj = 0; jj < 8; jj++) Vt[dbase + jj][key] = vv[jj];
            }
        }
        __syncthreads();

        // S^T = K Q^T : C[key][q], lane col = q = c, rows = 16*mt + 4*g + j
        f32x4 s[4];
#pragma unroll
        for (int mt = 0; mt < 4; mt++) {
            const bf16* krow = KP + (kvrow0 + k0 + mt * 16 + c) * 64;
            bf16x8 kb0 = *(const bf16x8*)(krow + g * 8);
            bf16x8 kb1 = *(const bf16x8*)(krow + 32 + g * 8);
            s[mt] = mfma16(kb0, qa[0], (f32x4){0.f, 0.f, 0.f, 0.f});
            s[mt] = mfma16(kb1, qa[1], s[mt]);
        }

        // mask + scale (lane's q = c: one uint2 covers keys k0..k0+63)
        uint2 wp = *(const uint2*)(bitrow + (k0 >> 5));
#pragma unroll
        for (int mt = 0; mt < 4; mt++)
#pragma unroll
            for (int j = 0; j < 4; j++) {
                int kl = mt * 16 + 4 * g + j;
                unsigned wsel = (kl < 32) ? wp.x : wp.y;
                s[mt][j] = ((wsel >> (kl & 31)) & 1) ? -1e30f : s[mt][j] * 0.125f;
            }

        // online softmax, lane-local row (16 vals) + 2 shfls
        float mx = -1e30f;
#pragma unroll
        for (int mt = 0; mt < 4; mt++)
            mx = fmaxf(mx, fmaxf(fmaxf(s[mt][0], s[mt][1]),
                                 fmaxf(s[mt][2], s[mt][3])));
        mx = fmaxf(mx, __shfl_xor(mx, 16, 64));
        mx = fmaxf(mx, __shfl_xor(mx, 32, 64));
        float mnew = fmaxf(m_r, mx);
        float fct = __expf(m_r - mnew);
        m_r = mnew;
        float sum = 0.f;
#pragma unroll
        for (int mt = 0; mt < 4; mt++)
#pragma unroll
            for (int j = 0; j < 4; j++) {
                float p = __expf(s[mt][j] - mnew);
                s[mt][j] = p;
                sum += p;
            }
        sum += __shfl_xor(sum, 16, 64);
        sum += __shfl_xor(sum, 32, 64);
        l_r = l_r * fct + sum;

        // write P row q=c: keys 16*mt+4*g..+3 contiguous -> b64 stores
#pragma unroll
        for (int mt = 0; mt < 4; mt++) {
            bf16x4 pk;
#pragma unroll
            for (int j = 0; j < 4; j++) pk[j] = (bf16)s[mt][j];
            *(bf16x4*)&Pl[wv][c][mt * 16 + 4 * g] = pk;
        }

        // broadcast fct to PV row layout (o_acc rows are q = 4*g+j)
        float fq[4];
#pragma unroll
        for (int j = 0; j < 4; j++)
            fq[j] = __shfl(fct, (lane & 48) | (4 * g + j), 64);
#pragma unroll
        for (int ot = 0; ot < 4; ot++)
#pragma unroll
            for (int j = 0; j < 4; j++) o_acc[ot][j] *= fq[j];

        asm volatile("s_waitcnt lgkmcnt(0)" ::: "memory");

        // PV: O[q][d] += P[q][k] Vt[d][k]
#pragma unroll
        for (int kh = 0; kh < 2; kh++) {
            bf16x8 pa = *(const bf16x8*)&Pl[wv][c][kh * 32 + g * 8];
#pragma unroll
            for (int ot = 0; ot < 4; ot++) {
                bf16x8 vb = *(const bf16x8*)&Vt[ot * 16 + c][kh * 32 + g * 8];
                o_acc[ot] = mfma16(pa, vb, o_acc[ot]);
            }
        }
    }

    float lq[4];
#pragma unroll
    for (int j = 0; j < 4; j++)
        lq[j] = __shfl(l_r, (lane & 48) | (4 * g + j), 64);
#pragma unroll
    for (int ot = 0; ot < 4; ot++)
#pragma unroll
        for (int j = 0; j < 4; j++)
            O[(qrow0 + 4 * g + j) * 64 + ot * 16 + c] =
                (bf16)(o_acc[ot][j] / lq[j]);
}

// ------------- LN(residual) -------------
__global__ __launch_bounds__(256) void ln_kernel(
    const float* __restrict__ res, const float* __restrict__ y,
    const float* __restrict__ g, const float* __restrict__ bb,
    float* __restrict__ outf, bf16* __restrict__ outb)
{
    int wave = threadIdx.x >> 6, lane = threadIdx.x & 63;
    long row = (long)blockIdx.x * 4 + wave;
    const float* rp = res + row * D_MODEL;
    const float* yp = y + row * D_MODEL;
    float v[8];
    float s = 0.f, sq = 0.f;
#pragma unroll
    for (int j = 0; j < 8; j++) {
        int col = lane + 64 * j;
        v[j] = rp[col] + yp[col];
        s += v[j]; sq += v[j] * v[j];
    }
#pragma unroll
    for (int o = 32; o > 0; o >>= 1) {
        s += __shfl_down(s, o, 64);
        sq += __shfl_down(sq, o, 64);
    }
    s = __shfl(s, 0, 64);
    sq = __shfl(sq, 0, 64);
    float mean = s * (1.f / 512.f);
    float var = sq * (1.f / 512.f) - mean * mean;
    float rstd = rsqrtf(fmaxf(var, 0.f) + 1e-5f);
    float* opf = outf + row * D_MODEL;
    bf16* opb = outb + row * D_MODEL;
#pragma unroll
    for (int j = 0; j < 8; j++) {
        int col = lane + 64 * j;
        float o = (v[j] - mean) * rstd * g[col] + bb[col];
        opf[col] = o;
        opb[col] = (bf16)o;
    }
}

extern "C" void kernel_launch(void* const* d_in, const int* in_sizes, int n_in,
                              void* d_out, int out_size, void* d_ws, size_t ws_size,
                              hipStream_t stream)
{
    const float* x    = (const float*)d_in[0];
    const float* hin  = (const float*)d_in[1];
    const int*   mask = (const int*)d_in[2];
    const float* wq   = (const float*)d_in[3];
    const float* wk   = (const float*)d_in[4];
    const float* wv   = (const float*)d_in[5];
    const float* wo   = (const float*)d_in[6];
    const float* ffw1 = (const float*)d_in[7];
    const float* ffb1 = (const float*)d_in[8];
    const float* ffw2 = (const float*)d_in[9];
    const float* ffb2 = (const float*)d_in[10];
    const float* g1   = (const float*)d_in[11];
    const float* be1  = (const float*)d_in[12];
    const float* g2   = (const float*)d_in[13];
    const float* be2  = (const float*)d_in[14];
    const float* out_wq = (const float*)d_in[15];
    const float* out_wk = (const float*)d_in[16];
    float* out = (float*)d_out;

    const long NQ = (long)BB * LQ;   // 4096
    const long NK = (long)BB * LKK;  // 8192
    const long WSZ = 512L * 512;     // 262144 elems per weight matrix
    const long KVS = NK * D_MODEL;   // 4194304 elems per K or V plane

    char* W = (char*)d_ws;
    float* h_f  = (float*)(W);                      //  8 MB
    float* y_f  = (float*)(W + 8388608);            //  8 MB
    bf16*  h_b  = (bf16*)(W + 16777216);            //  4 MB
    bf16*  x_b  = (bf16*)(W + 20971520);            //  8 MB
    bf16*  q_b  = (bf16*)(W + 29360128);            //  4 MB
    bf16*  a_b  = (bf16*)(W + 33554432);            //  4 MB
    bf16*  kv   = (bf16*)(W + 37748736);            // 16 MB (K_i, V_i; kf at end)
    bf16*  wtQ  = (bf16*)(W + 54525952);            // 1.5 MB
    bf16*  wtO  = (bf16*)(W + 56098816);            // 1.5 MB
    bf16*  wtF1 = (bf16*)(W + 57671680);            // 1.5 MB
    bf16*  wtF2 = (bf16*)(W + 59244544);            // 1.5 MB
    bf16*  wtKV = (bf16*)(W + 60817408);            // 3.5 MB [K0,V0,K1,V1,K2,V2,OutK]
    bf16*  wtOQ = (bf16*)(W + 64487424);            // 0.5 MB
    unsigned* mb = (unsigned*)(W + 65011712);       //  1 MB

    dim3 blk(256);

    // preprocessing
    hipMemcpyAsync(h_f, hin, NQ * D_MODEL * sizeof(float),
                   hipMemcpyDeviceToDevice, stream);
    cast_kernel<<<dim3((NK * D_MODEL / 4 + 255) / 256), blk, 0, stream>>>(x, x_b, NK * D_MODEL);
    cast_kernel<<<dim3((NQ * D_MODEL / 4 + 255) / 256), blk, 0, stream>>>(hin, h_b, NQ * D_MODEL);
    dim3 gt(16, 16, 3);
    tcast_kernel<<<gt, blk, 0, stream>>>(wq, wtQ, WSZ);
    tcast_kernel<<<gt, blk, 0, stream>>>(wo, wtO, WSZ);
    tcast_kernel<<<gt, blk, 0, stream>>>(ffw1, wtF1, WSZ);
    tcast_kernel<<<gt, blk, 0, stream>>>(ffw2, wtF2, WSZ);
    tcast_kernel<<<gt, blk, 0, stream>>>(wk, wtKV, 2 * WSZ);
    tcast_kernel<<<gt, blk, 0, stream>>>(wv, wtKV + WSZ, 2 * WSZ);
    dim3 gt1(16, 16, 1);
    tcast_kernel<<<gt1, blk, 0, stream>>>(out_wk, wtKV + 6 * WSZ, 0);
    tcast_kernel<<<gt1, blk, 0, stream>>>(out_wq, wtOQ, 0);
    maskbits_kernel<<<dim3(32768), blk, 0, stream>>>(mask, mb);

    dim3 gq(8, 32, 1);           // 4096 x 512 (128x64 tiles)
    dim3 gkv(4, 64, 2);          // 8192 x 512, z = {K,V} (128x128 tiles)
    dim3 ga(LQ / 64, BB * 8);

    for (int i = 0; i < NL; i++) {
        mfma_gemm<0,0,1><<<gq, blk, 0, stream>>>(h_b, wtQ + i * WSZ, nullptr, q_b,
            512, 512, 1.f, 0, 0, 0);
        mfma_gemm128<1><<<gkv, blk, 0, stream>>>(x_b, wtKV + 2 * i * WSZ, kv,
            512, 512, 1.f, 0, WSZ, KVS);

        attn_mfma<<<ga, blk, 0, stream>>>(q_b, kv, kv + KVS, mb, a_b);

        mfma_gemm<0,0,0><<<gq, blk, 0, stream>>>(a_b, wtO + i * WSZ, nullptr, y_f,
            512, 512, 1.f, 0, 0, 0);
        ln_kernel<<<dim3(NQ / 4), blk, 0, stream>>>(h_f, y_f,
            g1 + i * D_MODEL, be1 + i * D_MODEL, h_f, h_b);

        mfma_gemm<1,1,1><<<gq, blk, 0, stream>>>(h_b, wtF1 + i * WSZ,
            ffb1 + i * D_MODEL, q_b, 512, 512, 1.f, 0, 0, 0);
        mfma_gemm<1,0,0><<<gq, blk, 0, stream>>>(q_b, wtF2 + i * WSZ,
            ffb2 + i * D_MODEL, y_f, 512, 512, 1.f, 0, 0, 0);
        ln_kernel<<<dim3(NQ / 4), blk, 0, stream>>>(h_f, y_f,
            g2 + i * D_MODEL, be2 + i * D_MODEL, h_f, h_b);
    }

    // final scores: qf = h@out_wq ; kf = x@out_wk (into kv, now free) ;
    // out = qf @ kf^T / sqrt(512), batched over B.
    mfma_gemm<0,0,1><<<gq, blk, 0, stream>>>(h_b, wtOQ, nullptr, q_b,
        512, 512, 1.f, 0, 0, 0);
    dim3 gkf(4, 64, 1);
    mfma_gemm128<1><<<gkf, blk, 0, stream>>>(x_b, wtKV + 6 * WSZ, kv,
        512, 512, 1.f, 0, 0, 0);
    dim3 gf(LKK / 128, LQ / 128, BB);
    mfma_gemm128<0><<<gf, blk, 0, stream>>>(q_b, kv, out,
        LKK, 512, 0.04419417382415922f,
        (long)LQ * 512, (long)LKK * 512, (long)LQ * LKK);
}